// Round 1
// baseline (215.433 us; speedup 1.0000x reference)
//
#include <hip/hip_runtime.h>

#define N_IN 1024
#define N_OUT 1024
#define BATCHN 8192

typedef __attribute__((ext_vector_type(8))) short short8;
typedef __attribute__((ext_vector_type(4))) float floatx4;

__device__ __forceinline__ unsigned short f2bf(float f) {
  unsigned int u = __float_as_uint(f);
  u += 0x7FFFu + ((u >> 16) & 1u);
  return (unsigned short)(u >> 16);
}

// ---------------------------------------------------------------------------
// Kernel 1: per-row prep. gelu(x) -> bf16 (for MFMA GEMM), plus the 18-value
// segment summary (seg_x[9], seg_cnt[9]) per row, fp32.
// One wave per row; each lane handles 16 elements (4x float4, coalesced).
// ---------------------------------------------------------------------------
__global__ __launch_bounds__(64) void prep_rows(const float* __restrict__ x,
                                                unsigned short* __restrict__ g,
                                                float* __restrict__ seg) {
  const int row = blockIdx.x;
  const int lane = threadIdx.x;
  const float* xr = x + row * N_IN;
  unsigned short* gr = g + row * N_IN;
  float lx[9], lc[9];
#pragma unroll
  for (int s = 0; s < 9; ++s) { lx[s] = 0.f; lc[s] = 0.f; }
#pragma unroll
  for (int j = 0; j < 4; ++j) {
    float4 v4 = ((const float4*)xr)[lane + 64 * j];
    float vs[4] = {v4.x, v4.y, v4.z, v4.w};
    ushort4 o4;
#pragma unroll
    for (int e = 0; e < 4; ++e) {
      float v = vs[e];
      float gl = 0.5f * v * (1.0f + erff(v * 0.70710678f));  // exact gelu
      ((unsigned short*)&o4)[e] = f2bf(gl);
      int cnt = 0;
#pragma unroll
      for (int k = 0; k < 10; ++k)
        cnt += (v >= (-1.0f + (float)k * (2.0f / 9.0f))) ? 1 : 0;
      int sg = cnt - 1;
      sg = sg < 0 ? 0 : (sg > 8 ? 8 : sg);
#pragma unroll
      for (int s = 0; s < 9; ++s) {  // static-indexed bins (no scratch spill)
        lx[s] += (sg == s) ? v : 0.0f;
        lc[s] += (sg == s) ? 1.0f : 0.0f;
      }
    }
    ((ushort4*)gr)[lane + 64 * j] = o4;
  }
#pragma unroll
  for (int s = 0; s < 9; ++s) {
#pragma unroll
    for (int off = 32; off > 0; off >>= 1) {
      lx[s] += __shfl_xor(lx[s], off);
      lc[s] += __shfl_xor(lc[s], off);
    }
  }
  if (lane == 0) {
#pragma unroll
    for (int s = 0; s < 9; ++s) {
      seg[row * 18 + s] = lx[s];
      seg[row * 18 + 9 + s] = lc[s];
    }
  }
}

// ---------------------------------------------------------------------------
// Kernel 2: weights fp32 -> bf16 (blocks 0..1023), plus transpose of
// slopes[:,0,:] / intercepts[:,0,:] into coalesced [9][1024] fp32 (block 1024).
// ---------------------------------------------------------------------------
__global__ __launch_bounds__(256) void prep_w(const float* __restrict__ W,
                                              unsigned short* __restrict__ Wb,
                                              const float* __restrict__ slopes,
                                              const float* __restrict__ icpts,
                                              float* __restrict__ slt,
                                              float* __restrict__ ict) {
  const int b = blockIdx.x;
  const int t = threadIdx.x;
  if (b < N_OUT) {
    float4 v = ((const float4*)(W + b * N_IN))[t];
    ushort4 o;
    o.x = f2bf(v.x);
    o.y = f2bf(v.y);
    o.z = f2bf(v.z);
    o.w = f2bf(v.w);
    ((ushort4*)(Wb + b * N_IN))[t] = o;
  } else {
    for (int i = t; i < N_OUT * 9; i += 256) {
      int o = i / 9, s = i - o * 9;
      slt[s * N_OUT + o] = slopes[(long)o * 9216 + s];  // slopes[o][0][s]
      ict[s * N_OUT + o] = icpts[(long)o * 9216 + s];
    }
  }
}

// ---------------------------------------------------------------------------
// Kernel 3: bf16 MFMA GEMM, C[m][n] = sum_k A[m][k]*B[n][k], fp32 out.
// 128x128 tile, BK=32, 4 waves (2x2 of 64x64), 16x16x32 MFMA,
// global_load_lds width=16 staging (m97 structure).
// ---------------------------------------------------------------------------
#define ASYNC_CP16(gp, lp)                                                     \
  __builtin_amdgcn_global_load_lds(                                            \
      (const __attribute__((address_space(1))) unsigned int*)(gp),             \
      (__attribute__((address_space(3))) unsigned int*)(lp), 16, 0, 0)

__global__ __launch_bounds__(256) void gemm_bt(const unsigned short* __restrict__ A,
                                               const unsigned short* __restrict__ B,
                                               float* __restrict__ C) {
  const int K = N_IN;
  __shared__ unsigned short lA[128 * 32];
  __shared__ unsigned short lB[128 * 32];
  const int t = threadIdx.x;
  const int m0 = blockIdx.x * 128;  // x = m-tile: blocks sharing A-slab -> same XCD
  const int n0 = blockIdx.y * 128;
  const int lane = t & 63, wv = t >> 6;
  const int wm = (wv >> 1) * 64, wn = (wv & 1) * 64;
  floatx4 acc[4][4] = {};

  const int r = t >> 2;          // 0..63: row within tile
  const int c8 = (t & 3) * 8;    // element offset within BK
  const unsigned short* Ab = A + (m0 + r) * K + c8;
  const unsigned short* Bb = B + (n0 + r) * K + c8;
  unsigned short* lAp = &lA[r * 32 + c8];
  unsigned short* lBp = &lB[r * 32 + c8];

  const int arow = wm + (lane & 15);
  const int brow = wn + (lane & 15);
  const int koff = (lane >> 4) * 8;

  for (int kt = 0; kt < K / 32; ++kt) {
    __syncthreads();
    const int ko = kt * 32;
    ASYNC_CP16(Ab + ko, lAp);
    ASYNC_CP16(Ab + ko + 64 * K, lAp + 64 * 32);
    ASYNC_CP16(Bb + ko, lBp);
    ASYNC_CP16(Bb + ko + 64 * K, lBp + 64 * 32);
    __syncthreads();
    short8 af[4], bf[4];
#pragma unroll
    for (int i = 0; i < 4; ++i)
      af[i] = *(const short8*)&lA[(arow + i * 16) * 32 + koff];
#pragma unroll
    for (int i = 0; i < 4; ++i)
      bf[i] = *(const short8*)&lB[(brow + i * 16) * 32 + koff];
#pragma unroll
    for (int mi = 0; mi < 4; ++mi)
#pragma unroll
      for (int ni = 0; ni < 4; ++ni)
        acc[mi][ni] =
            __builtin_amdgcn_mfma_f32_16x16x32_bf16(af[mi], bf[ni], acc[mi][ni], 0, 0, 0);
  }

  // C/D layout: col = lane&15, row = (lane>>4)*4 + reg  [m89-verified]
  const int crow0 = m0 + wm + (lane >> 4) * 4;
  const int ccol0 = n0 + wn + (lane & 15);
#pragma unroll
  for (int mi = 0; mi < 4; ++mi)
#pragma unroll
    for (int ni = 0; ni < 4; ++ni)
#pragma unroll
      for (int rg = 0; rg < 4; ++rg)
        C[(crow0 + mi * 16 + rg) * N_OUT + ccol0 + ni * 16] = acc[mi][ni][rg];
}

// ---------------------------------------------------------------------------
// Kernel 4: y = C + bias + lin(seg);  LayerNorm (two-pass) + PReLU, in place.
// 512 threads: thread t owns cols t and t+512 (slopes held in registers),
// 16 rows per block.
// ---------------------------------------------------------------------------
__global__ __launch_bounds__(512) void ln_prelu(float* __restrict__ C,
                                                const float* __restrict__ biases,
                                                const float* __restrict__ seg,
                                                const float* __restrict__ slt,
                                                const float* __restrict__ ict,
                                                const float* __restrict__ prelu_w) {
  const int t = threadIdx.x;
  const int o1 = t, o2 = t + 512;
  const int lane = t & 63, wv = t >> 6;
  const float b1 = biases[o1], b2 = biases[o2];
  float sl1[9], sl2[9], ic1[9], ic2[9];
#pragma unroll
  for (int s = 0; s < 9; ++s) {
    sl1[s] = slt[s * N_OUT + o1];
    sl2[s] = slt[s * N_OUT + o2];
    ic1[s] = ict[s * N_OUT + o1];
    ic2[s] = ict[s * N_OUT + o2];
  }
  const float pw = prelu_w[0];
  __shared__ float red[8];
  __shared__ float stat[2];
  for (int r = 0; r < 16; ++r) {
    const int row = blockIdx.x * 16 + r;
    const float* segr = seg + row * 18;
    float y1 = C[row * N_OUT + o1] + b1;
    float y2 = C[row * N_OUT + o2] + b2;
#pragma unroll
    for (int s = 0; s < 9; ++s) {
      float sx = segr[s], ct = segr[9 + s];
      y1 += sx * sl1[s] + ct * ic1[s];
      y2 += sx * sl2[s] + ct * ic2[s];
    }
    float sum = y1 + y2;
#pragma unroll
    for (int off = 32; off > 0; off >>= 1) sum += __shfl_xor(sum, off);
    if (lane == 0) red[wv] = sum;
    __syncthreads();
    if (t == 0) {
      float s2 = 0.f;
#pragma unroll
      for (int i = 0; i < 8; ++i) s2 += red[i];
      stat[0] = s2 * (1.0f / 1024.0f);
    }
    __syncthreads();
    const float mu = stat[0];
    const float d1 = y1 - mu, d2 = y2 - mu;
    float sq = d1 * d1 + d2 * d2;
#pragma unroll
    for (int off = 32; off > 0; off >>= 1) sq += __shfl_xor(sq, off);
    if (lane == 0) red[wv] = sq;
    __syncthreads();
    if (t == 0) {
      float s2 = 0.f;
#pragma unroll
      for (int i = 0; i < 8; ++i) s2 += red[i];
      stat[1] = rsqrtf(s2 * (1.0f / 1024.0f) + 1e-5f);
    }
    __syncthreads();
    const float rstd = stat[1];
    float z1 = d1 * rstd, z2 = d2 * rstd;
    z1 = z1 >= 0.f ? z1 : pw * z1;
    z2 = z2 >= 0.f ? z2 : pw * z2;
    C[row * N_OUT + o1] = z1;
    C[row * N_OUT + o2] = z2;
    __syncthreads();
  }
}

extern "C" void kernel_launch(void* const* d_in, const int* in_sizes, int n_in,
                              void* d_out, int out_size, void* d_ws, size_t ws_size,
                              hipStream_t stream) {
  const float* x = (const float*)d_in[0];
  const float* W = (const float*)d_in[1];
  const float* biases = (const float*)d_in[2];
  const float* slopes = (const float*)d_in[3];
  const float* icpts = (const float*)d_in[4];
  const float* prelu_w = (const float*)d_in[5];
  float* C = (float*)d_out;

  char* ws = (char*)d_ws;
  unsigned short* g = (unsigned short*)ws;                      // 16 MB bf16 gelu(x)
  unsigned short* Wb = (unsigned short*)(ws + (16u << 20));     // 2 MB bf16 W
  float* seg = (float*)(ws + (18u << 20));                      // 8192*18 fp32
  float* slt = (float*)(ws + (19u << 20));                      // 9*1024 fp32
  float* ict = (float*)(ws + (19u << 20) + (64u << 10));        // 9*1024 fp32

  prep_rows<<<BATCHN, 64, 0, stream>>>(x, g, seg);
  prep_w<<<N_OUT + 1, 256, 0, stream>>>(W, Wb, slopes, icpts, slt, ict);
  gemm_bt<<<dim3(BATCHN / 128, N_OUT / 128), 256, 0, stream>>>(g, Wb, C);
  ln_prelu<<<BATCHN / 16, 512, 0, stream>>>(C, biases, seg, slt, ict, prelu_w);
}

// Round 2
// 190.984 us; speedup vs baseline: 1.1280x; 1.1280x over previous
//
#include <hip/hip_runtime.h>

#define N_IN 1024
#define N_OUT 1024
#define BATCHN 8192
#define BK 64

typedef __attribute__((ext_vector_type(8))) short short8;
typedef __attribute__((ext_vector_type(4))) float floatx4;

__device__ __forceinline__ unsigned short f2bf(float f) {
  unsigned int u = __float_as_uint(f);
  u += 0x7FFFu + ((u >> 16) & 1u);
  return (unsigned short)(u >> 16);
}

// ---------------------------------------------------------------------------
// Kernel 1 (merged prep): 3136 blocks x 256 threads.
//  blocks [0, 2048):    rows — 4 waves/block, one row each: gelu(x)->bf16 + seg summary
//  blocks [2048, 3072): weights fp32 -> bf16, one row each
//  blocks [3072, 3136): slopes/intercepts [:,0,:] gather-transpose, fully parallel
// ---------------------------------------------------------------------------
__global__ __launch_bounds__(256) void prep_all(const float* __restrict__ x,
                                                unsigned short* __restrict__ g,
                                                float* __restrict__ seg,
                                                const float* __restrict__ W,
                                                unsigned short* __restrict__ Wb,
                                                const float* __restrict__ slopes,
                                                const float* __restrict__ icpts,
                                                float* __restrict__ slt,
                                                float* __restrict__ ict) {
  const int b = blockIdx.x;
  const int t = threadIdx.x;
  if (b < BATCHN / 4) {
    const int lane = t & 63, wv = t >> 6;
    const int row = b * 4 + wv;
    const float* xr = x + row * N_IN;
    unsigned short* gr = g + row * N_IN;
    float lx[9], lc[9];
#pragma unroll
    for (int s = 0; s < 9; ++s) { lx[s] = 0.f; lc[s] = 0.f; }
#pragma unroll
    for (int j = 0; j < 4; ++j) {
      float4 v4 = ((const float4*)xr)[lane + 64 * j];
      float vs[4] = {v4.x, v4.y, v4.z, v4.w};
      ushort4 o4;
#pragma unroll
      for (int e = 0; e < 4; ++e) {
        float v = vs[e];
        float gl = 0.5f * v * (1.0f + erff(v * 0.70710678f));  // exact gelu
        ((unsigned short*)&o4)[e] = f2bf(gl);
        int cnt = 0;
#pragma unroll
        for (int k = 0; k < 10; ++k)
          cnt += (v >= (-1.0f + (float)k * (2.0f / 9.0f))) ? 1 : 0;
        int sg = cnt - 1;
        sg = sg < 0 ? 0 : (sg > 8 ? 8 : sg);
#pragma unroll
        for (int s = 0; s < 9; ++s) {
          lx[s] += (sg == s) ? v : 0.0f;
          lc[s] += (sg == s) ? 1.0f : 0.0f;
        }
      }
      ((ushort4*)gr)[lane + 64 * j] = o4;
    }
#pragma unroll
    for (int s = 0; s < 9; ++s) {
#pragma unroll
      for (int off = 32; off > 0; off >>= 1) {
        lx[s] += __shfl_xor(lx[s], off);
        lc[s] += __shfl_xor(lc[s], off);
      }
    }
    if (lane == 0) {
#pragma unroll
      for (int s = 0; s < 9; ++s) {
        seg[row * 18 + s] = lx[s];
        seg[row * 18 + 9 + s] = lc[s];
      }
    }
  } else if (b < BATCHN / 4 + N_OUT) {
    const int o = b - BATCHN / 4;
    float4 v = ((const float4*)(W + o * N_IN))[t];
    ushort4 u;
    u.x = f2bf(v.x);
    u.y = f2bf(v.y);
    u.z = f2bf(v.z);
    u.w = f2bf(v.w);
    ((ushort4*)(Wb + o * N_IN))[t] = u;
  } else {
    const int gb = b - (BATCHN / 4 + N_OUT);  // 0..63
    const int o = gb * 16 + (t >> 4);
    const int s = t & 15;
    if (s < 9) {
      slt[s * N_OUT + o] = slopes[(long)o * 9216 + s];  // slopes[o][0][s]
      ict[s * N_OUT + o] = icpts[(long)o * 9216 + s];
    }
  }
}

// ---------------------------------------------------------------------------
// Kernel 2: bf16 MFMA GEMM, C[m][n] = sum_k A[m][k]*B[n][k], fp32 out.
// 128x128 tile, BK=64 (16 barrier-drains instead of 32), 4 waves (2x2 of
// 64x64), 16x16x32 MFMA, global_load_lds width=16.
// XOR chunk swizzle: logical 16B chunk c of row r is stored at physical
// chunk c^(r&7). global_load_lds forces LDS addr = lane*16 + uniform base,
// but the *global* source per lane is free — so swizzle the source. MFMA
// fragment reads then spread 16 consecutive rows over all 32 banks
// (2 lanes/bank = free) instead of 8-way conflicts.
// ---------------------------------------------------------------------------
#define ASYNC_CP16(gp, lp)                                                     \
  __builtin_amdgcn_global_load_lds(                                            \
      (const __attribute__((address_space(1))) unsigned int*)(gp),             \
      (__attribute__((address_space(3))) unsigned int*)(lp), 16, 0, 0)

__global__ __launch_bounds__(256) void gemm_bt(const unsigned short* __restrict__ A,
                                               const unsigned short* __restrict__ B,
                                               float* __restrict__ C) {
  __shared__ unsigned short lA[128 * BK];  // 16 KB
  __shared__ unsigned short lB[128 * BK];  // 16 KB
  const int t = threadIdx.x;
  const int m0 = blockIdx.x * 128;
  const int n0 = blockIdx.y * 128;
  const int lane = t & 63, wv = t >> 6;
  const int wm = (wv >> 1) * 64, wn = (wv & 1) * 64;
  floatx4 acc[4][4] = {};

  const int arow = wm + (lane & 15);
  const int brow = wn + (lane & 15);
  const int kq = lane >> 4;  // 0..3: which 8-elem k-chunk within a 32-chunk

  for (int kt = 0; kt < N_IN / BK; ++kt) {
    __syncthreads();
    const int ko = kt * BK;
#pragma unroll
    for (int j = 0; j < 4; ++j) {
      const int sg = t + 256 * j;       // 16B segment id; LDS byte = sg*16
      const int r = sg >> 3;            // row 0..127
      const int l = (sg & 7) ^ (r & 7); // logical chunk for this physical slot
      ASYNC_CP16(A + (m0 + r) * N_IN + ko + l * 8, &lA[sg * 8]);
    }
#pragma unroll
    for (int j = 0; j < 4; ++j) {
      const int sg = t + 256 * j;
      const int r = sg >> 3;
      const int l = (sg & 7) ^ (r & 7);
      ASYNC_CP16(B + (n0 + r) * N_IN + ko + l * 8, &lB[sg * 8]);
    }
    __syncthreads();
#pragma unroll
    for (int kk = 0; kk < 2; ++kk) {
      short8 af[4], bf[4];
#pragma unroll
      for (int i = 0; i < 4; ++i) {
        const int row = arow + i * 16;
        const int pc = (kk * 4 + kq) ^ (row & 7);
        af[i] = *(const short8*)&lA[row * BK + pc * 8];
      }
#pragma unroll
      for (int i = 0; i < 4; ++i) {
        const int row = brow + i * 16;
        const int pc = (kk * 4 + kq) ^ (row & 7);
        bf[i] = *(const short8*)&lB[row * BK + pc * 8];
      }
#pragma unroll
      for (int mi = 0; mi < 4; ++mi)
#pragma unroll
        for (int ni = 0; ni < 4; ++ni)
          acc[mi][ni] = __builtin_amdgcn_mfma_f32_16x16x32_bf16(af[mi], bf[ni],
                                                                acc[mi][ni], 0, 0, 0);
    }
  }

  // C/D layout: col = lane&15, row = (lane>>4)*4 + reg  [m89-verified]
  const int crow0 = m0 + wm + (lane >> 4) * 4;
  const int ccol0 = n0 + wn + (lane & 15);
#pragma unroll
  for (int mi = 0; mi < 4; ++mi)
#pragma unroll
    for (int ni = 0; ni < 4; ++ni)
#pragma unroll
      for (int rg = 0; rg < 4; ++rg)
        C[(crow0 + mi * 16 + rg) * N_OUT + ccol0 + ni * 16] = acc[mi][ni][rg];
}

// ---------------------------------------------------------------------------
// Kernel 3: y = C + bias + lin(seg); LayerNorm + PReLU in place.
// Single-pass sum/sumsq (|mu|~1 << std~20, no cancellation risk), butterfly
// both through one shuffle chain, every thread sums the 8 wave partials
// itself (no serial thread, no broadcast barrier), double-buffered LDS slots
// -> exactly 1 __syncthreads per row. 1024 blocks x 8 rows for latency hiding.
// ---------------------------------------------------------------------------
__global__ __launch_bounds__(512) void ln_prelu(float* __restrict__ C,
                                                const float* __restrict__ biases,
                                                const float* __restrict__ seg,
                                                const float* __restrict__ slt,
                                                const float* __restrict__ ict,
                                                const float* __restrict__ prelu_w) {
  const int t = threadIdx.x;
  const int o1 = t, o2 = t + 512;
  const int lane = t & 63, wv = t >> 6;
  const float b1 = biases[o1], b2 = biases[o2];
  float sl1[9], sl2[9], ic1[9], ic2[9];
#pragma unroll
  for (int s = 0; s < 9; ++s) {
    sl1[s] = slt[s * N_OUT + o1];
    sl2[s] = slt[s * N_OUT + o2];
    ic1[s] = ict[s * N_OUT + o1];
    ic2[s] = ict[s * N_OUT + o2];
  }
  const float pw = prelu_w[0];
  __shared__ float2 red[2][8];
  for (int r = 0; r < 8; ++r) {
    const int row = blockIdx.x * 8 + r;
    const float* segr = seg + row * 18;
    float y1 = C[row * N_OUT + o1] + b1;
    float y2 = C[row * N_OUT + o2] + b2;
#pragma unroll
    for (int s = 0; s < 9; ++s) {
      float sx = segr[s], ct = segr[9 + s];
      y1 += sx * sl1[s] + ct * ic1[s];
      y2 += sx * sl2[s] + ct * ic2[s];
    }
    float sum = y1 + y2;
    float sq = y1 * y1 + y2 * y2;
#pragma unroll
    for (int off = 32; off > 0; off >>= 1) {
      sum += __shfl_xor(sum, off);
      sq += __shfl_xor(sq, off);
    }
    if (lane == 0) red[r & 1][wv] = make_float2(sum, sq);
    __syncthreads();
    float s8 = 0.f, q8 = 0.f;
#pragma unroll
    for (int i = 0; i < 8; ++i) {
      s8 += red[r & 1][i].x;
      q8 += red[r & 1][i].y;
    }
    const float mu = s8 * (1.0f / 1024.0f);
    const float var = q8 * (1.0f / 1024.0f) - mu * mu;
    const float rstd = rsqrtf(var + 1e-5f);
    float z1 = (y1 - mu) * rstd, z2 = (y2 - mu) * rstd;
    z1 = z1 >= 0.f ? z1 : pw * z1;
    z2 = z2 >= 0.f ? z2 : pw * z2;
    C[row * N_OUT + o1] = z1;
    C[row * N_OUT + o2] = z2;
  }
}

extern "C" void kernel_launch(void* const* d_in, const int* in_sizes, int n_in,
                              void* d_out, int out_size, void* d_ws, size_t ws_size,
                              hipStream_t stream) {
  const float* x = (const float*)d_in[0];
  const float* W = (const float*)d_in[1];
  const float* biases = (const float*)d_in[2];
  const float* slopes = (const float*)d_in[3];
  const float* icpts = (const float*)d_in[4];
  const float* prelu_w = (const float*)d_in[5];
  float* C = (float*)d_out;

  char* ws = (char*)d_ws;
  unsigned short* g = (unsigned short*)ws;                   // 16 MB bf16 gelu(x)
  unsigned short* Wb = (unsigned short*)(ws + (16u << 20));  // 2 MB bf16 W
  float* seg = (float*)(ws + (18u << 20));                   // 8192*18 fp32
  float* slt = (float*)(ws + (19u << 20));                   // 9*1024 fp32
  float* ict = (float*)(ws + (19u << 20) + (64u << 10));     // 9*1024 fp32

  prep_all<<<BATCHN / 4 + N_OUT + 64, 256, 0, stream>>>(x, g, seg, W, Wb, slopes,
                                                        icpts, slt, ict);
  gemm_bt<<<dim3(BATCHN / 128, N_OUT / 128), 256, 0, stream>>>(g, Wb, C);
  ln_prelu<<<BATCHN / 8, 512, 0, stream>>>(C, biases, seg, slt, ict, prelu_w);
}

// Round 3
// 184.436 us; speedup vs baseline: 1.1681x; 1.0355x over previous
//
#include <hip/hip_runtime.h>

#define N_IN 1024
#define N_OUT 1024
#define BATCHN 8192
#define BK 64

typedef __attribute__((ext_vector_type(8))) short short8;
typedef __attribute__((ext_vector_type(16))) float floatx16;

__device__ __forceinline__ unsigned short f2bf(float f) {
  unsigned int u = __float_as_uint(f);
  u += 0x7FFFu + ((u >> 16) & 1u);
  return (unsigned short)(u >> 16);
}
__device__ __forceinline__ float bf2f(unsigned short s) {
  return __uint_as_float(((unsigned int)s) << 16);
}

// ---------------------------------------------------------------------------
// Kernel 1 (merged prep): 3136 blocks x 256 threads.
//  blocks [0, 2048):    rows — 4 waves/block, one row each: gelu(x)->bf16 +
//                       segment summary via CUMULATIVE thresholds (8 interior
//                       grid points; bins are differences — 24 ops/elem vs 54)
//  blocks [2048, 3072): weights fp32 -> bf16, one row each
//  blocks [3072, 3136): slopes/intercepts [:,0,:] gather-transpose
// ---------------------------------------------------------------------------
__global__ __launch_bounds__(256) void prep_all(const float* __restrict__ x,
                                                unsigned short* __restrict__ g,
                                                float* __restrict__ seg,
                                                const float* __restrict__ W,
                                                unsigned short* __restrict__ Wb,
                                                const float* __restrict__ slopes,
                                                const float* __restrict__ icpts,
                                                float* __restrict__ slt,
                                                float* __restrict__ ict) {
  const int b = blockIdx.x;
  const int t = threadIdx.x;
  if (b < BATCHN / 4) {
    const int lane = t & 63, wv = t >> 6;
    const int row = b * 4 + wv;
    const float* xr = x + row * N_IN;
    unsigned short* gr = g + row * N_IN;
    float cum[8], cumx[8], totx = 0.f;
#pragma unroll
    for (int s = 0; s < 8; ++s) { cum[s] = 0.f; cumx[s] = 0.f; }
#pragma unroll
    for (int j = 0; j < 4; ++j) {
      float4 v4 = ((const float4*)xr)[lane + 64 * j];
      float vs[4] = {v4.x, v4.y, v4.z, v4.w};
      ushort4 o4;
#pragma unroll
      for (int e = 0; e < 4; ++e) {
        float v = vs[e];
        float gl = 0.5f * v * (1.0f + erff(v * 0.70710678f));  // exact gelu
        ((unsigned short*)&o4)[e] = f2bf(gl);
        totx += v;
#pragma unroll
        for (int k = 0; k < 8; ++k) {
          bool m = v >= (-1.0f + (float)(k + 1) * (2.0f / 9.0f));
          cum[k] += m ? 1.0f : 0.0f;
          cumx[k] += m ? v : 0.0f;
        }
      }
      ((ushort4*)gr)[lane + 64 * j] = o4;
    }
#pragma unroll
    for (int off = 32; off > 0; off >>= 1) {
      totx += __shfl_xor(totx, off);
#pragma unroll
      for (int s = 0; s < 8; ++s) {
        cum[s] += __shfl_xor(cum[s], off);
        cumx[s] += __shfl_xor(cumx[s], off);
      }
    }
    if (lane == 0) {
      float sx[9], sc[9];
      sx[0] = totx - cumx[0];
      sc[0] = 1024.f - cum[0];
#pragma unroll
      for (int s = 1; s < 8; ++s) {
        sx[s] = cumx[s - 1] - cumx[s];
        sc[s] = cum[s - 1] - cum[s];
      }
      sx[8] = cumx[7];
      sc[8] = cum[7];
#pragma unroll
      for (int s = 0; s < 9; ++s) {
        seg[row * 18 + s] = sx[s];
        seg[row * 18 + 9 + s] = sc[s];
      }
    }
  } else if (b < BATCHN / 4 + N_OUT) {
    const int o = b - BATCHN / 4;
    float4 v = ((const float4*)(W + o * N_IN))[t];
    ushort4 u;
    u.x = f2bf(v.x);
    u.y = f2bf(v.y);
    u.z = f2bf(v.z);
    u.w = f2bf(v.w);
    ((ushort4*)(Wb + o * N_IN))[t] = u;
  } else {
    const int gb = b - (BATCHN / 4 + N_OUT);  // 0..63
    const int o = gb * 16 + (t >> 4);
    const int s = t & 15;
    if (s < 9) {
      slt[s * N_OUT + o] = slopes[(long)o * 9216 + s];  // slopes[o][0][s]
      ict[s * N_OUT + o] = icpts[(long)o * 9216 + s];
    }
  }
}

// ---------------------------------------------------------------------------
// Kernel 2: bf16 MFMA GEMM, Cb[m][n] = sum_k A[m][k]*B[n][k], bf16 out.
// 128x128 tile, BK=64, 4 waves (2x2 of 64x64), 32x32x16 MFMA (4060 FLOP/cyc
// vs 3378 for 16x16x32 — m119), global_load_lds width=16, XOR chunk swizzle
// (logical chunk c of row r stored at physical c^(r&7); fragment reads spread
// 32 rows over all banks at the minimum 4-deep b128 cadence).
// ---------------------------------------------------------------------------
#define ASYNC_CP16(gp, lp)                                                     \
  __builtin_amdgcn_global_load_lds(                                            \
      (const __attribute__((address_space(1))) unsigned int*)(gp),             \
      (__attribute__((address_space(3))) unsigned int*)(lp), 16, 0, 0)

__global__ __launch_bounds__(256) void gemm_bt(const unsigned short* __restrict__ A,
                                               const unsigned short* __restrict__ B,
                                               unsigned short* __restrict__ Cb) {
  __shared__ unsigned short lA[128 * BK];  // 16 KB
  __shared__ unsigned short lB[128 * BK];  // 16 KB
  const int t = threadIdx.x;
  const int m0 = blockIdx.x * 128;
  const int n0 = blockIdx.y * 128;
  const int lane = t & 63, wv = t >> 6;
  const int wm = (wv >> 1) * 64, wn = (wv & 1) * 64;
  floatx16 acc[2][2] = {};

  const int l31 = lane & 31;
  const int lh = lane >> 5;  // 0/1: k-half within a 16-chunk

  for (int kt = 0; kt < N_IN / BK; ++kt) {
    __syncthreads();
    const int ko = kt * BK;
#pragma unroll
    for (int j = 0; j < 4; ++j) {
      const int sg = t + 256 * j;        // 16B segment id; LDS byte = sg*16
      const int r = sg >> 3;             // row 0..127
      const int l = (sg & 7) ^ (r & 7);  // logical chunk for this physical slot
      ASYNC_CP16(A + (m0 + r) * N_IN + ko + l * 8, &lA[sg * 8]);
    }
#pragma unroll
    for (int j = 0; j < 4; ++j) {
      const int sg = t + 256 * j;
      const int r = sg >> 3;
      const int l = (sg & 7) ^ (r & 7);
      ASYNC_CP16(B + (n0 + r) * N_IN + ko + l * 8, &lB[sg * 8]);
    }
    __syncthreads();
#pragma unroll
    for (int kk = 0; kk < 4; ++kk) {  // 4 x K16 per BK=64
      const int kc = kk * 2 + lh;     // logical 8-elem chunk
      short8 af[2], bf[2];
#pragma unroll
      for (int i = 0; i < 2; ++i) {
        const int row = wm + i * 32 + l31;
        af[i] = *(const short8*)&lA[row * BK + ((kc ^ (row & 7)) * 8)];
      }
#pragma unroll
      for (int i = 0; i < 2; ++i) {
        const int row = wn + i * 32 + l31;
        bf[i] = *(const short8*)&lB[row * BK + ((kc ^ (row & 7)) * 8)];
      }
#pragma unroll
      for (int mi = 0; mi < 2; ++mi)
#pragma unroll
        for (int ni = 0; ni < 2; ++ni)
          acc[mi][ni] = __builtin_amdgcn_mfma_f32_32x32x16_bf16(af[mi], bf[ni],
                                                                acc[mi][ni], 0, 0, 0);
    }
  }

  // 32x32 C/D layout: col = lane&31, row = (rg&3) + 8*(rg>>2) + 4*(lane>>5)
  // [m74/m101-verified]
  const int lrow = 4 * lh;
#pragma unroll
  for (int mi = 0; mi < 2; ++mi)
#pragma unroll
    for (int ni = 0; ni < 2; ++ni)
#pragma unroll
      for (int rg = 0; rg < 16; ++rg) {
        const int r = m0 + wm + mi * 32 + (rg & 3) + 8 * (rg >> 2) + lrow;
        const int c = n0 + wn + ni * 32 + l31;
        Cb[r * N_OUT + c] = f2bf(acc[mi][ni][rg]);
      }
}

// ---------------------------------------------------------------------------
// Kernel 3: y = Cb(bf16) + bias + lin(seg); LayerNorm + PReLU -> fp32 out.
// Single-pass sum/sumsq, one __syncthreads per row (double-buffered LDS
// partials), every thread sums the 8 wave partials itself.
// ---------------------------------------------------------------------------
__global__ __launch_bounds__(512) void ln_prelu(const unsigned short* __restrict__ Cb,
                                                float* __restrict__ out,
                                                const float* __restrict__ biases,
                                                const float* __restrict__ seg,
                                                const float* __restrict__ slt,
                                                const float* __restrict__ ict,
                                                const float* __restrict__ prelu_w) {
  const int t = threadIdx.x;
  const int o1 = t, o2 = t + 512;
  const int lane = t & 63, wv = t >> 6;
  const float b1 = biases[o1], b2 = biases[o2];
  float sl1[9], sl2[9], ic1[9], ic2[9];
#pragma unroll
  for (int s = 0; s < 9; ++s) {
    sl1[s] = slt[s * N_OUT + o1];
    sl2[s] = slt[s * N_OUT + o2];
    ic1[s] = ict[s * N_OUT + o1];
    ic2[s] = ict[s * N_OUT + o2];
  }
  const float pw = prelu_w[0];
  __shared__ float2 red[2][8];
  for (int r = 0; r < 8; ++r) {
    const int row = blockIdx.x * 8 + r;
    const float* segr = seg + row * 18;
    float y1 = bf2f(Cb[row * N_OUT + o1]) + b1;
    float y2 = bf2f(Cb[row * N_OUT + o2]) + b2;
#pragma unroll
    for (int s = 0; s < 9; ++s) {
      float sx = segr[s], ct = segr[9 + s];
      y1 += sx * sl1[s] + ct * ic1[s];
      y2 += sx * sl2[s] + ct * ic2[s];
    }
    float sum = y1 + y2;
    float sq = y1 * y1 + y2 * y2;
#pragma unroll
    for (int off = 32; off > 0; off >>= 1) {
      sum += __shfl_xor(sum, off);
      sq += __shfl_xor(sq, off);
    }
    if (lane == 0) red[r & 1][wv] = make_float2(sum, sq);
    __syncthreads();
    float s8 = 0.f, q8 = 0.f;
#pragma unroll
    for (int i = 0; i < 8; ++i) {
      s8 += red[r & 1][i].x;
      q8 += red[r & 1][i].y;
    }
    const float mu = s8 * (1.0f / 1024.0f);
    const float var = q8 * (1.0f / 1024.0f) - mu * mu;
    const float rstd = rsqrtf(var + 1e-5f);
    float z1 = (y1 - mu) * rstd, z2 = (y2 - mu) * rstd;
    z1 = z1 >= 0.f ? z1 : pw * z1;
    z2 = z2 >= 0.f ? z2 : pw * z2;
    out[row * N_OUT + o1] = z1;
    out[row * N_OUT + o2] = z2;
  }
}

extern "C" void kernel_launch(void* const* d_in, const int* in_sizes, int n_in,
                              void* d_out, int out_size, void* d_ws, size_t ws_size,
                              hipStream_t stream) {
  const float* x = (const float*)d_in[0];
  const float* W = (const float*)d_in[1];
  const float* biases = (const float*)d_in[2];
  const float* slopes = (const float*)d_in[3];
  const float* icpts = (const float*)d_in[4];
  const float* prelu_w = (const float*)d_in[5];
  float* out = (float*)d_out;

  char* ws = (char*)d_ws;
  unsigned short* g = (unsigned short*)ws;                   // 16 MB bf16 gelu(x)
  unsigned short* Wb = (unsigned short*)(ws + (16u << 20));  // 2 MB bf16 W
  unsigned short* Cb = (unsigned short*)(ws + (18u << 20));  // 16 MB bf16 C
  float* seg = (float*)(ws + (34u << 20));                   // 8192*18 fp32
  float* slt = (float*)(ws + (35u << 20));                   // 9*1024 fp32
  float* ict = (float*)(ws + (35u << 20) + (64u << 10));     // 9*1024 fp32

  prep_all<<<BATCHN / 4 + N_OUT + 64, 256, 0, stream>>>(x, g, seg, W, Wb, slopes,
                                                        icpts, slt, ict);
  gemm_bt<<<dim3(BATCHN / 128, N_OUT / 128), 256, 0, stream>>>(g, Wb, Cb);
  ln_prelu<<<BATCHN / 8, 512, 0, stream>>>(Cb, out, biases, seg, slt, ict, prelu_w);
}

// Round 4
// 175.782 us; speedup vs baseline: 1.2256x; 1.0492x over previous
//
#include <hip/hip_runtime.h>
#include <hip/hip_fp8.h>

#define N_IN 1024
#define N_OUT 1024
#define BATCHN 8192

typedef __attribute__((ext_vector_type(4))) int intx4;
typedef __attribute__((ext_vector_type(8))) int intx8;
typedef __attribute__((ext_vector_type(16))) float floatx16;

__device__ __forceinline__ unsigned short f2bf(float f) {
  unsigned int u = __float_as_uint(f);
  u += 0x7FFFu + ((u >> 16) & 1u);
  return (unsigned short)(u >> 16);
}
__device__ __forceinline__ float bf2f(unsigned short s) {
  return __uint_as_float(((unsigned int)s) << 16);
}
__device__ __forceinline__ unsigned int f2e4m3(float f) {  // OCP e4m3fn byte
  __hip_fp8_e4m3 v(f);
  return (unsigned int)v.__x;
}

// ---------------------------------------------------------------------------
// Kernel 1 (merged prep): 3136 blocks x 256 threads.
//  blocks [0, 2048):    rows — gelu(x) -> fp8 e4m3 (scaled x4) + segment
//                       summary via cumulative thresholds
//  blocks [2048, 3072): weights -> fp8 e4m3 (scaled x16)
//  blocks [3072, 3136): slopes/intercepts [:,0,:] gather-transpose
// Scales are undone in-hardware by the MX e8m0 scale operands (2^-2 * 2^-4).
// ---------------------------------------------------------------------------
__global__ __launch_bounds__(256) void prep_all(const float* __restrict__ x,
                                                unsigned char* __restrict__ g8,
                                                float* __restrict__ seg,
                                                const float* __restrict__ W,
                                                unsigned char* __restrict__ Wb8,
                                                const float* __restrict__ slopes,
                                                const float* __restrict__ icpts,
                                                float* __restrict__ slt,
                                                float* __restrict__ ict) {
  const int b = blockIdx.x;
  const int t = threadIdx.x;
  if (b < BATCHN / 4) {
    const int lane = t & 63, wv = t >> 6;
    const int row = b * 4 + wv;
    const float* xr = x + row * N_IN;
    unsigned int* gr = (unsigned int*)(g8 + row * N_IN);
    float cum[8], cumx[8], totx = 0.f;
#pragma unroll
    for (int s = 0; s < 8; ++s) { cum[s] = 0.f; cumx[s] = 0.f; }
#pragma unroll
    for (int j = 0; j < 4; ++j) {
      float4 v4 = ((const float4*)xr)[lane + 64 * j];
      float vs[4] = {v4.x, v4.y, v4.z, v4.w};
      unsigned int pk = 0;
#pragma unroll
      for (int e = 0; e < 4; ++e) {
        float v = vs[e];
        float gl = 0.5f * v * (1.0f + erff(v * 0.70710678f));  // exact gelu
        pk |= f2e4m3(gl * 4.0f) << (8 * e);                    // x4 scale
        totx += v;
#pragma unroll
        for (int k = 0; k < 8; ++k) {
          bool m = v >= (-1.0f + (float)(k + 1) * (2.0f / 9.0f));
          cum[k] += m ? 1.0f : 0.0f;
          cumx[k] += m ? v : 0.0f;
        }
      }
      gr[lane + 64 * j] = pk;
    }
#pragma unroll
    for (int off = 32; off > 0; off >>= 1) {
      totx += __shfl_xor(totx, off);
#pragma unroll
      for (int s = 0; s < 8; ++s) {
        cum[s] += __shfl_xor(cum[s], off);
        cumx[s] += __shfl_xor(cumx[s], off);
      }
    }
    if (lane == 0) {
      float sx[9], sc[9];
      sx[0] = totx - cumx[0];
      sc[0] = 1024.f - cum[0];
#pragma unroll
      for (int s = 1; s < 8; ++s) {
        sx[s] = cumx[s - 1] - cumx[s];
        sc[s] = cum[s - 1] - cum[s];
      }
      sx[8] = cumx[7];
      sc[8] = cum[7];
#pragma unroll
      for (int s = 0; s < 9; ++s) {
        seg[row * 18 + s] = sx[s];
        seg[row * 18 + 9 + s] = sc[s];
      }
    }
  } else if (b < BATCHN / 4 + N_OUT) {
    const int o = b - BATCHN / 4;
    float4 v = ((const float4*)(W + o * N_IN))[t];
    unsigned int pk = f2e4m3(v.x * 16.0f) | (f2e4m3(v.y * 16.0f) << 8) |
                      (f2e4m3(v.z * 16.0f) << 16) | (f2e4m3(v.w * 16.0f) << 24);
    ((unsigned int*)(Wb8 + o * N_IN))[t] = pk;
  } else {
    const int gb = b - (BATCHN / 4 + N_OUT);  // 0..63
    const int o = gb * 16 + (t >> 4);
    const int s = t & 15;
    if (s < 9) {
      slt[s * N_OUT + o] = slopes[(long)o * 9216 + s];  // slopes[o][0][s]
      ict[s * N_OUT + o] = icpts[(long)o * 9216 + s];
    }
  }
}

// ---------------------------------------------------------------------------
// Kernel 2: MX-fp8 MFMA GEMM, Cb[m][n] = sum_k A[m][k]*B[n][k], bf16 out.
// 128x128 tile, BK=128 fp8 bytes (8 K-steps), 4 waves (2x2 of 64x64),
// mfma_scale_f32_32x32x64_f8f6f4 (1.9x bf16 FLOP/cyc, half LDS bytes),
// global_load_lds width=16.
// Rows are 128 B in LDS (8 x 16B chunks); physical chunk pc holds logical
// chunk pc^(r&7): fragment reads (32 consecutive rows, fixed logical chunk)
// then spread uniformly over all 32 banks — b128 floor, no extra conflicts.
// A/B per-lane layout: row = lane&31, k-half = lane>>5, 32 contiguous fp8
// (4x extension of the m74-verified 32x32x16 bf16 mapping, which round-3's
// passing kernel used).
// ---------------------------------------------------------------------------
#define ASYNC_CP16(gp, lp)                                                     \
  __builtin_amdgcn_global_load_lds(                                            \
      (const __attribute__((address_space(1))) unsigned int*)(gp),             \
      (__attribute__((address_space(3))) unsigned int*)(lp), 16, 0, 0)

__global__ __launch_bounds__(256) void gemm_bt(const unsigned char* __restrict__ A,
                                               const unsigned char* __restrict__ B,
                                               unsigned short* __restrict__ Cb) {
  __shared__ unsigned char lA[128 * 128];  // 16 KB
  __shared__ unsigned char lB[128 * 128];  // 16 KB
  const int t = threadIdx.x;
  const int m0 = blockIdx.x * 128;
  const int n0 = blockIdx.y * 128;
  const int lane = t & 63, wv = t >> 6;
  const int wm = (wv >> 1) * 64, wn = (wv & 1) * 64;
  floatx16 acc[2][2] = {};

  const int l31 = lane & 31;
  const int lh = lane >> 5;  // 0/1: k-half (32 contiguous fp8) within K64

  for (int kt = 0; kt < N_IN / 128; ++kt) {
    __syncthreads();
    const int ko = kt * 128;
#pragma unroll
    for (int j = 0; j < 4; ++j) {
      const int sg = t + 256 * j;        // 16B slot id; LDS byte = sg*16
      const int r = sg >> 3;             // row 0..127
      const int lc = (sg & 7) ^ (r & 7); // logical chunk stored in this slot
      ASYNC_CP16(A + (m0 + r) * N_IN + ko + lc * 16, &lA[sg * 16]);
    }
#pragma unroll
    for (int j = 0; j < 4; ++j) {
      const int sg = t + 256 * j;
      const int r = sg >> 3;
      const int lc = (sg & 7) ^ (r & 7);
      ASYNC_CP16(B + (n0 + r) * N_IN + ko + lc * 16, &lB[sg * 16]);
    }
    __syncthreads();
#pragma unroll
    for (int kk = 0; kk < 2; ++kk) {  // 2 x K64 per BK128
      const int lc0 = kk * 4 + lh * 2;
      intx8 af[2], bf[2];
#pragma unroll
      for (int i = 0; i < 2; ++i) {
        const int row = wm + i * 32 + l31;
        const int sw = row & 7;
        intx4 lo = *(const intx4*)&lA[row * 128 + ((lc0 ^ sw) * 16)];
        intx4 hi = *(const intx4*)&lA[row * 128 + (((lc0 + 1) ^ sw) * 16)];
        af[i][0] = lo[0]; af[i][1] = lo[1]; af[i][2] = lo[2]; af[i][3] = lo[3];
        af[i][4] = hi[0]; af[i][5] = hi[1]; af[i][6] = hi[2]; af[i][7] = hi[3];
      }
#pragma unroll
      for (int i = 0; i < 2; ++i) {
        const int row = wn + i * 32 + l31;
        const int sw = row & 7;
        intx4 lo = *(const intx4*)&lB[row * 128 + ((lc0 ^ sw) * 16)];
        intx4 hi = *(const intx4*)&lB[row * 128 + (((lc0 + 1) ^ sw) * 16)];
        bf[i][0] = lo[0]; bf[i][1] = lo[1]; bf[i][2] = lo[2]; bf[i][3] = lo[3];
        bf[i][4] = hi[0]; bf[i][5] = hi[1]; bf[i][6] = hi[2]; bf[i][7] = hi[3];
      }
#pragma unroll
      for (int mi = 0; mi < 2; ++mi)
#pragma unroll
        for (int ni = 0; ni < 2; ++ni)
          acc[mi][ni] = __builtin_amdgcn_mfma_scale_f32_32x32x64_f8f6f4(
              af[mi], bf[ni], acc[mi][ni], 0 /*cbsz: A=fp8*/, 0 /*blgp: B=fp8*/,
              0, 0x7D7D7D7Du /*A scale 2^-2*/, 0, 0x7B7B7B7Bu /*B scale 2^-4*/);
    }
  }

  // 32x32 C/D layout (shape-determined): col = lane&31,
  // row = (rg&3) + 8*(rg>>2) + 4*(lane>>5)   [m74/m101/m121-128]
  const int lrow = 4 * lh;
#pragma unroll
  for (int mi = 0; mi < 2; ++mi)
#pragma unroll
    for (int ni = 0; ni < 2; ++ni)
#pragma unroll
      for (int rg = 0; rg < 16; ++rg) {
        const int r = m0 + wm + mi * 32 + (rg & 3) + 8 * (rg >> 2) + lrow;
        const int c = n0 + wn + ni * 32 + l31;
        Cb[r * N_OUT + c] = f2bf(acc[mi][ni][rg]);
      }
}

// ---------------------------------------------------------------------------
// Kernel 3: y = Cb(bf16) + bias + lin(seg); LayerNorm + PReLU -> fp32 out.
// Thread t owns adjacent cols 2t, 2t+1 (ushort2 read / float2 write).
// Single-pass sum/sumsq, one __syncthreads per row.
// ---------------------------------------------------------------------------
__global__ __launch_bounds__(512) void ln_prelu(const unsigned short* __restrict__ Cb,
                                                float* __restrict__ out,
                                                const float* __restrict__ biases,
                                                const float* __restrict__ seg,
                                                const float* __restrict__ slt,
                                                const float* __restrict__ ict,
                                                const float* __restrict__ prelu_w) {
  const int t = threadIdx.x;
  const int o = 2 * t;
  const int lane = t & 63, wv = t >> 6;
  const float b1 = biases[o], b2 = biases[o + 1];
  float sl1[9], sl2[9], ic1[9], ic2[9];
#pragma unroll
  for (int s = 0; s < 9; ++s) {
    sl1[s] = slt[s * N_OUT + o];
    sl2[s] = slt[s * N_OUT + o + 1];
    ic1[s] = ict[s * N_OUT + o];
    ic2[s] = ict[s * N_OUT + o + 1];
  }
  const float pw = prelu_w[0];
  __shared__ float2 red[2][8];
  for (int r = 0; r < 8; ++r) {
    const int row = blockIdx.x * 8 + r;
    const float* segr = seg + row * 18;
    ushort2 cc = *(const ushort2*)&Cb[row * N_OUT + o];
    float y1 = bf2f(cc.x) + b1;
    float y2 = bf2f(cc.y) + b2;
#pragma unroll
    for (int s = 0; s < 9; ++s) {
      float sx = segr[s], ct = segr[9 + s];
      y1 += sx * sl1[s] + ct * ic1[s];
      y2 += sx * sl2[s] + ct * ic2[s];
    }
    float sum = y1 + y2;
    float sq = y1 * y1 + y2 * y2;
#pragma unroll
    for (int off = 32; off > 0; off >>= 1) {
      sum += __shfl_xor(sum, off);
      sq += __shfl_xor(sq, off);
    }
    if (lane == 0) red[r & 1][wv] = make_float2(sum, sq);
    __syncthreads();
    float s8 = 0.f, q8 = 0.f;
#pragma unroll
    for (int i = 0; i < 8; ++i) {
      s8 += red[r & 1][i].x;
      q8 += red[r & 1][i].y;
    }
    const float mu = s8 * (1.0f / 1024.0f);
    const float var = q8 * (1.0f / 1024.0f) - mu * mu;
    const float rstd = rsqrtf(var + 1e-5f);
    float z1 = (y1 - mu) * rstd, z2 = (y2 - mu) * rstd;
    z1 = z1 >= 0.f ? z1 : pw * z1;
    z2 = z2 >= 0.f ? z2 : pw * z2;
    *(float2*)&out[row * N_OUT + o] = make_float2(z1, z2);
  }
}

extern "C" void kernel_launch(void* const* d_in, const int* in_sizes, int n_in,
                              void* d_out, int out_size, void* d_ws, size_t ws_size,
                              hipStream_t stream) {
  const float* x = (const float*)d_in[0];
  const float* W = (const float*)d_in[1];
  const float* biases = (const float*)d_in[2];
  const float* slopes = (const float*)d_in[3];
  const float* icpts = (const float*)d_in[4];
  const float* prelu_w = (const float*)d_in[5];
  float* out = (float*)d_out;

  char* ws = (char*)d_ws;
  unsigned char* g8 = (unsigned char*)ws;                    // 8 MB fp8 4*gelu(x)
  unsigned char* Wb8 = (unsigned char*)(ws + (8u << 20));    // 1 MB fp8 16*W
  unsigned short* Cb = (unsigned short*)(ws + (16u << 20));  // 16 MB bf16 C
  float* seg = (float*)(ws + (33u << 20));                   // 8192*18 fp32
  float* slt = (float*)(ws + (34u << 20));                   // 9*1024 fp32
  float* ict = (float*)(ws + (34u << 20) + (64u << 10));     // 9*1024 fp32

  prep_all<<<BATCHN / 4 + N_OUT + 64, 256, 0, stream>>>(x, g8, seg, W, Wb8, slopes,
                                                        icpts, slt, ict);
  gemm_bt<<<dim3(BATCHN / 128, N_OUT / 128), 256, 0, stream>>>(g8, Wb8, Cb);
  ln_prelu<<<BATCHN / 8, 512, 0, stream>>>(Cb, out, biases, seg, slt, ict, prelu_w);
}

// Round 5
// 166.602 us; speedup vs baseline: 1.2931x; 1.0551x over previous
//
#include <hip/hip_runtime.h>
#include <hip/hip_fp8.h>

#define N_IN 1024
#define N_OUT 1024
#define BATCHN 8192

typedef __attribute__((ext_vector_type(4))) int intx4;
typedef __attribute__((ext_vector_type(8))) int intx8;
typedef __attribute__((ext_vector_type(16))) float floatx16;
typedef __attribute__((ext_vector_type(2))) float f32x2;

__device__ __forceinline__ unsigned short f2bf(float f) {
  unsigned int u = __float_as_uint(f);
  u += 0x7FFFu + ((u >> 16) & 1u);
  return (unsigned short)(u >> 16);
}
__device__ __forceinline__ float bf2f(unsigned short s) {
  return __uint_as_float(((unsigned int)s) << 16);
}
__device__ __forceinline__ unsigned int f2e4m3(float f) {  // OCP e4m3fn byte
  __hip_fp8_e4m3 v(f);
  return (unsigned int)v.__x;
}
// gelu ~= v * sigmoid(1.702 v) = v * rcp(1 + exp2(-2.4554 v)).
// Max abs err ~0.02 — below the fp8 e4m3 quantization noise of the GEMM path.
__device__ __forceinline__ float gelu_fast(float v) {
  float e = __builtin_amdgcn_exp2f(-2.4554443f * v);
  return v * __builtin_amdgcn_rcpf(1.0f + e);
}

// ---------------------------------------------------------------------------
// Kernel 1 (merged prep): 3136 blocks x 256 threads.
//  blocks [0, 2048):    rows — gelu(x) -> fp8 e4m3 (scaled x4) + segment
//                       summary via cumulative thresholds
//  blocks [2048, 3072): weights -> fp8 e4m3 (scaled x16)
//  blocks [3072, 3136): slopes/intercepts [:,0,:] gather-transpose
// Scales are undone in-hardware by the MX e8m0 scale operands (2^-2 * 2^-4).
// ---------------------------------------------------------------------------
__global__ __launch_bounds__(256) void prep_all(const float* __restrict__ x,
                                                unsigned char* __restrict__ g8,
                                                float* __restrict__ seg,
                                                const float* __restrict__ W,
                                                unsigned char* __restrict__ Wb8,
                                                const float* __restrict__ slopes,
                                                const float* __restrict__ icpts,
                                                float* __restrict__ slt,
                                                float* __restrict__ ict) {
  const int b = blockIdx.x;
  const int t = threadIdx.x;
  if (b < BATCHN / 4) {
    const int lane = t & 63, wv = t >> 6;
    const int row = b * 4 + wv;
    const float* xr = x + row * N_IN;
    unsigned int* gr = (unsigned int*)(g8 + row * N_IN);
    float cum[8], cumx[8], totx = 0.f;
#pragma unroll
    for (int s = 0; s < 8; ++s) { cum[s] = 0.f; cumx[s] = 0.f; }
#pragma unroll
    for (int j = 0; j < 4; ++j) {
      float4 v4 = ((const float4*)xr)[lane + 64 * j];
      float vs[4] = {v4.x, v4.y, v4.z, v4.w};
      unsigned int pk = 0;
#pragma unroll
      for (int e = 0; e < 4; ++e) {
        float v = vs[e];
        pk |= f2e4m3(gelu_fast(v) * 4.0f) << (8 * e);  // x4 scale
        totx += v;
#pragma unroll
        for (int k = 0; k < 8; ++k) {
          bool m = v >= (-1.0f + (float)(k + 1) * (2.0f / 9.0f));
          cum[k] += m ? 1.0f : 0.0f;
          cumx[k] += m ? v : 0.0f;
        }
      }
      gr[lane + 64 * j] = pk;
    }
#pragma unroll
    for (int off = 32; off > 0; off >>= 1) {
      totx += __shfl_xor(totx, off);
#pragma unroll
      for (int s = 0; s < 8; ++s) {
        cum[s] += __shfl_xor(cum[s], off);
        cumx[s] += __shfl_xor(cumx[s], off);
      }
    }
    if (lane == 0) {
      float sx[9], sc[9];
      sx[0] = totx - cumx[0];
      sc[0] = 1024.f - cum[0];
#pragma unroll
      for (int s = 1; s < 8; ++s) {
        sx[s] = cumx[s - 1] - cumx[s];
        sc[s] = cum[s - 1] - cum[s];
      }
      sx[8] = cumx[7];
      sc[8] = cum[7];
#pragma unroll
      for (int s = 0; s < 9; ++s) {
        seg[row * 18 + s] = sx[s];
        seg[row * 18 + 9 + s] = sc[s];
      }
    }
  } else if (b < BATCHN / 4 + N_OUT) {
    const int o = b - BATCHN / 4;
    float4 v = ((const float4*)(W + o * N_IN))[t];
    unsigned int pk = f2e4m3(v.x * 16.0f) | (f2e4m3(v.y * 16.0f) << 8) |
                      (f2e4m3(v.z * 16.0f) << 16) | (f2e4m3(v.w * 16.0f) << 24);
    ((unsigned int*)(Wb8 + o * N_IN))[t] = pk;
  } else {
    const int gb = b - (BATCHN / 4 + N_OUT);  // 0..63
    const int o = gb * 16 + (t >> 4);
    const int s = t & 15;
    if (s < 9) {
      slt[s * N_OUT + o] = slopes[(long)o * 9216 + s];  // slopes[o][0][s]
      ict[s * N_OUT + o] = icpts[(long)o * 9216 + s];
    }
  }
}

// ---------------------------------------------------------------------------
// Kernel 2: MX-fp8 MFMA GEMM, Cb[m][n] = sum_k A[m][k]*B[n][k], bf16 out.
// 128x128 tile, BK=128 fp8 bytes (8 K-steps), 4 waves (2x2 of 64x64),
// mfma_scale_f32_32x32x64_f8f6f4, global_load_lds width=16, XOR chunk
// swizzle (physical 16B chunk pc of row r holds logical chunk pc^(r&7)).
// ---------------------------------------------------------------------------
#define ASYNC_CP16(gp, lp)                                                     \
  __builtin_amdgcn_global_load_lds(                                            \
      (const __attribute__((address_space(1))) unsigned int*)(gp),             \
      (__attribute__((address_space(3))) unsigned int*)(lp), 16, 0, 0)

__global__ __launch_bounds__(256) void gemm_bt(const unsigned char* __restrict__ A,
                                               const unsigned char* __restrict__ B,
                                               unsigned short* __restrict__ Cb) {
  __shared__ unsigned char lA[128 * 128];  // 16 KB
  __shared__ unsigned char lB[128 * 128];  // 16 KB
  const int t = threadIdx.x;
  const int m0 = blockIdx.x * 128;
  const int n0 = blockIdx.y * 128;
  const int lane = t & 63, wv = t >> 6;
  const int wm = (wv >> 1) * 64, wn = (wv & 1) * 64;
  floatx16 acc[2][2] = {};

  const int l31 = lane & 31;
  const int lh = lane >> 5;  // 0/1: k-half (32 contiguous fp8) within K64

  for (int kt = 0; kt < N_IN / 128; ++kt) {
    __syncthreads();
    const int ko = kt * 128;
#pragma unroll
    for (int j = 0; j < 4; ++j) {
      const int sg = t + 256 * j;         // 16B slot id; LDS byte = sg*16
      const int r = sg >> 3;              // row 0..127
      const int lc = (sg & 7) ^ (r & 7);  // logical chunk stored in this slot
      ASYNC_CP16(A + (m0 + r) * N_IN + ko + lc * 16, &lA[sg * 16]);
    }
#pragma unroll
    for (int j = 0; j < 4; ++j) {
      const int sg = t + 256 * j;
      const int r = sg >> 3;
      const int lc = (sg & 7) ^ (r & 7);
      ASYNC_CP16(B + (n0 + r) * N_IN + ko + lc * 16, &lB[sg * 16]);
    }
    __syncthreads();
#pragma unroll
    for (int kk = 0; kk < 2; ++kk) {  // 2 x K64 per BK128
      const int lc0 = kk * 4 + lh * 2;
      intx8 af[2], bf[2];
#pragma unroll
      for (int i = 0; i < 2; ++i) {
        const int row = wm + i * 32 + l31;
        const int sw = row & 7;
        intx4 lo = *(const intx4*)&lA[row * 128 + ((lc0 ^ sw) * 16)];
        intx4 hi = *(const intx4*)&lA[row * 128 + (((lc0 + 1) ^ sw) * 16)];
        af[i][0] = lo[0]; af[i][1] = lo[1]; af[i][2] = lo[2]; af[i][3] = lo[3];
        af[i][4] = hi[0]; af[i][5] = hi[1]; af[i][6] = hi[2]; af[i][7] = hi[3];
      }
#pragma unroll
      for (int i = 0; i < 2; ++i) {
        const int row = wn + i * 32 + l31;
        const int sw = row & 7;
        intx4 lo = *(const intx4*)&lB[row * 128 + ((lc0 ^ sw) * 16)];
        intx4 hi = *(const intx4*)&lB[row * 128 + (((lc0 + 1) ^ sw) * 16)];
        bf[i][0] = lo[0]; bf[i][1] = lo[1]; bf[i][2] = lo[2]; bf[i][3] = lo[3];
        bf[i][4] = hi[0]; bf[i][5] = hi[1]; bf[i][6] = hi[2]; bf[i][7] = hi[3];
      }
#pragma unroll
      for (int mi = 0; mi < 2; ++mi)
#pragma unroll
        for (int ni = 0; ni < 2; ++ni)
          acc[mi][ni] = __builtin_amdgcn_mfma_scale_f32_32x32x64_f8f6f4(
              af[mi], bf[ni], acc[mi][ni], 0 /*cbsz: A=fp8*/, 0 /*blgp: B=fp8*/,
              0, 0x7D7D7D7Du /*A scale 2^-2*/, 0, 0x7B7B7B7Bu /*B scale 2^-4*/);
    }
  }

  // 32x32 C/D layout (shape-determined): col = lane&31,
  // row = (rg&3) + 8*(rg>>2) + 4*(lane>>5)   [m74/m101/m121-128]
  const int lrow = 4 * lh;
#pragma unroll
  for (int mi = 0; mi < 2; ++mi)
#pragma unroll
    for (int ni = 0; ni < 2; ++ni)
#pragma unroll
      for (int rg = 0; rg < 16; ++rg) {
        const int r = m0 + wm + mi * 32 + (rg & 3) + 8 * (rg >> 2) + lrow;
        const int c = n0 + wn + ni * 32 + l31;
        Cb[r * N_OUT + c] = f2bf(acc[mi][ni][rg]);
      }
}

// ---------------------------------------------------------------------------
// Kernel 3: y = Cb(bf16) + bias + lin(seg); LayerNorm + PReLU -> fp32 out.
// Thread t owns adjacent cols 2t, 2t+1. TWO rows per iteration (both rows'
// loads in flight, one barrier per pair, partials in a float4 slot).
// out written with nontemporal stores (never re-read; keep L2 for Cb).
// ---------------------------------------------------------------------------
__global__ __launch_bounds__(512) void ln_prelu(const unsigned short* __restrict__ Cb,
                                                float* __restrict__ out,
                                                const float* __restrict__ biases,
                                                const float* __restrict__ seg,
                                                const float* __restrict__ slt,
                                                const float* __restrict__ ict,
                                                const float* __restrict__ prelu_w) {
  const int t = threadIdx.x;
  const int o = 2 * t;
  const int lane = t & 63, wv = t >> 6;
  const float2 bb = *(const float2*)&biases[o];
  float sl1[9], sl2[9], ic1[9], ic2[9];
#pragma unroll
  for (int s = 0; s < 9; ++s) {
    float2 sv = *(const float2*)&slt[s * N_OUT + o];
    float2 iv = *(const float2*)&ict[s * N_OUT + o];
    sl1[s] = sv.x; sl2[s] = sv.y;
    ic1[s] = iv.x; ic2[s] = iv.y;
  }
  const float pw = prelu_w[0];
  __shared__ float4 red[2][8];
  for (int it = 0; it < 4; ++it) {
    const int rowA = blockIdx.x * 8 + it * 2;
    const int rowB = rowA + 1;
    const float* segA = seg + rowA * 18;
    const float* segB = seg + rowB * 18;
    ushort2 ca = *(const ushort2*)&Cb[rowA * N_OUT + o];
    ushort2 cb = *(const ushort2*)&Cb[rowB * N_OUT + o];
    float ya1 = bf2f(ca.x) + bb.x, ya2 = bf2f(ca.y) + bb.y;
    float yb1 = bf2f(cb.x) + bb.x, yb2 = bf2f(cb.y) + bb.y;
#pragma unroll
    for (int s = 0; s < 9; ++s) {
      float sxa = segA[s], cta = segA[9 + s];
      float sxb = segB[s], ctb = segB[9 + s];
      ya1 += sxa * sl1[s] + cta * ic1[s];
      ya2 += sxa * sl2[s] + cta * ic2[s];
      yb1 += sxb * sl1[s] + ctb * ic1[s];
      yb2 += sxb * sl2[s] + ctb * ic2[s];
    }
    float sa = ya1 + ya2, qa = ya1 * ya1 + ya2 * ya2;
    float sb = yb1 + yb2, qb = yb1 * yb1 + yb2 * yb2;
#pragma unroll
    for (int off = 32; off > 0; off >>= 1) {
      sa += __shfl_xor(sa, off);
      qa += __shfl_xor(qa, off);
      sb += __shfl_xor(sb, off);
      qb += __shfl_xor(qb, off);
    }
    if (lane == 0) red[it & 1][wv] = make_float4(sa, qa, sb, qb);
    __syncthreads();
    float s8a = 0.f, q8a = 0.f, s8b = 0.f, q8b = 0.f;
#pragma unroll
    for (int i = 0; i < 8; ++i) {
      float4 p = red[it & 1][i];
      s8a += p.x; q8a += p.y; s8b += p.z; q8b += p.w;
    }
    const float muA = s8a * (1.0f / 1024.0f);
    const float rstdA = rsqrtf(q8a * (1.0f / 1024.0f) - muA * muA + 1e-5f);
    const float muB = s8b * (1.0f / 1024.0f);
    const float rstdB = rsqrtf(q8b * (1.0f / 1024.0f) - muB * muB + 1e-5f);
    float za1 = (ya1 - muA) * rstdA, za2 = (ya2 - muA) * rstdA;
    float zb1 = (yb1 - muB) * rstdB, zb2 = (yb2 - muB) * rstdB;
    za1 = za1 >= 0.f ? za1 : pw * za1;
    za2 = za2 >= 0.f ? za2 : pw * za2;
    zb1 = zb1 >= 0.f ? zb1 : pw * zb1;
    zb2 = zb2 >= 0.f ? zb2 : pw * zb2;
    f32x2 va = {za1, za2}, vb = {zb1, zb2};
    __builtin_nontemporal_store(va, (f32x2*)&out[rowA * N_OUT + o]);
    __builtin_nontemporal_store(vb, (f32x2*)&out[rowB * N_OUT + o]);
  }
}

extern "C" void kernel_launch(void* const* d_in, const int* in_sizes, int n_in,
                              void* d_out, int out_size, void* d_ws, size_t ws_size,
                              hipStream_t stream) {
  const float* x = (const float*)d_in[0];
  const float* W = (const float*)d_in[1];
  const float* biases = (const float*)d_in[2];
  const float* slopes = (const float*)d_in[3];
  const float* icpts = (const float*)d_in[4];
  const float* prelu_w = (const float*)d_in[5];
  float* out = (float*)d_out;

  char* ws = (char*)d_ws;
  unsigned char* g8 = (unsigned char*)ws;                    // 8 MB fp8 4*gelu(x)
  unsigned char* Wb8 = (unsigned char*)(ws + (8u << 20));    // 1 MB fp8 16*W
  unsigned short* Cb = (unsigned short*)(ws + (16u << 20));  // 16 MB bf16 C
  float* seg = (float*)(ws + (33u << 20));                   // 8192*18 fp32
  float* slt = (float*)(ws + (34u << 20));                   // 9*1024 fp32
  float* ict = (float*)(ws + (34u << 20) + (64u << 10));     // 9*1024 fp32

  prep_all<<<BATCHN / 4 + N_OUT + 64, 256, 0, stream>>>(x, g8, seg, W, Wb8, slopes,
                                                        icpts, slt, ict);
  gemm_bt<<<dim3(BATCHN / 128, N_OUT / 128), 256, 0, stream>>>(g8, Wb8, Cb);
  ln_prelu<<<BATCHN / 8, 512, 0, stream>>>(Cb, out, biases, seg, slt, ict, prelu_w);
}